// Round 3
// baseline (2012.875 us; speedup 1.0000x reference)
//
#include <hip/hip_runtime.h>
#include <hip/hip_bf16.h>

typedef unsigned short u16;
typedef unsigned int   u32;

#define V_N 100000
#define E_N 1600000
#define NIN 128
#define EIN 50
#define HH  50

typedef __attribute__((ext_vector_type(8))) short bf16x8;
typedef __attribute__((ext_vector_type(4))) float f32x4;

__device__ __forceinline__ float bf2f(u16 u) {
    union { u32 i; float f; } v; v.i = ((u32)u) << 16; return v.f;
}
__device__ __forceinline__ u16 f2bf(float f) {
    union { float f; u32 i; } v; v.f = f;
    u32 x = v.i;
    return (u16)((x + 0x7fffu + ((x >> 16) & 1u)) >> 16);
}
// XOR swizzle: flips bits 3..5 of the element-in-row index (16B granules within
// each 128B sub-block). Breaks the 16-way bank conflict of stride-384B/-128B rows.
__device__ __forceinline__ int swz(int row, int k) { return k ^ ((row & 7) << 3); }

// ---------------------------------------------------------------------------
// Kernel A: left = nf @ w_l + b_l, right = nf @ w_r + b_r  (bf16 out to ws)
// (unchanged — known-correct; ~120 us est., next-round target)
// ---------------------------------------------------------------------------
__global__ __launch_bounds__(256) void k_lr(
    const float* __restrict__ nf,
    const float* __restrict__ w1, const float* __restrict__ b1,
    const float* __restrict__ w2, const float* __restrict__ b2,
    u16* __restrict__ left, u16* __restrict__ right)
{
    __shared__ u16 sw[2 * NIN * HH];
    __shared__ u16 sx[64 * NIN];
    __shared__ float sb[2 * HH];

    const int tid = threadIdx.x;
    for (int i = tid; i < NIN * HH; i += 256) {
        sw[i]          = f2bf(w1[i]);
        sw[NIN*HH + i] = f2bf(w2[i]);
    }
    if (tid < HH) {
        sb[tid]      = b1[tid];
        sb[HH + tid] = b2[tid];
    }
    const int row0 = blockIdx.x * 64;
    const float4* nf4 = (const float4*)nf;
    const int base4 = row0 * (NIN / 4);
    for (int i = tid; i < 64 * NIN / 4; i += 256) {
        float4 v = make_float4(0.f, 0.f, 0.f, 0.f);
        if (base4 + i < V_N * NIN / 4) v = nf4[base4 + i];
        ushort4 p;
        p.x = f2bf(v.x); p.y = f2bf(v.y); p.z = f2bf(v.z); p.w = f2bf(v.w);
        ((ushort4*)sx)[i] = p;
    }
    __syncthreads();

    for (int t = tid; t < 8 * HH; t += 256) {
        const int rt = t / HH, c = t - rt * HH;
        float a1[8], a2[8];
        #pragma unroll
        for (int j = 0; j < 8; ++j) { a1[j] = sb[c]; a2[j] = sb[HH+c]; }
        const u16* xr = &sx[rt * 8 * NIN];
        for (int k = 0; k < NIN; ++k) {
            const float wv1 = bf2f(sw[k*HH + c]);
            const float wv2 = bf2f(sw[NIN*HH + k*HH + c]);
            #pragma unroll
            for (int j = 0; j < 8; ++j) {
                const float x = bf2f(xr[j*NIN + k]);
                a1[j] = fmaf(x, wv1, a1[j]);
                a2[j] = fmaf(x, wv2, a2[j]);
            }
        }
        #pragma unroll
        for (int j = 0; j < 8; ++j) {
            const int r = row0 + rt*8 + j;
            if (r < V_N) {
                left [(size_t)r*HH + c] = f2bf(a1[j]);
                right[(size_t)r*HH + c] = f2bf(a2[j]);
            }
        }
    }
}

// ---------------------------------------------------------------------------
// Kernel B (MFMA rewrite): per 64 edges.
//   sint [64][192] bf16 (swizzled rows): k' 0..49 = first, 64..113 = second,
//     128..177 = third; pads zeroed (NaN-safe vs zero weights).
//   buf  [24576B]: stage1 = {wAt[64][64] | wBt[64][64] | sef[64][64]} (bf16,
//     transposed weights [n][k]); stage2 = swUt[64][192].
//   stage1: MFMA e2n=relu(ef@wA) -> atomicAdd(acc[dst]); third -> sint.
//   gather: first/second from left/right -> sint.
//   stage2: MFMA new_edge = relu(sint @ swUt + bU) -> fp32 out.
// ---------------------------------------------------------------------------
__global__ __launch_bounds__(256) void k_edge(
    const float* __restrict__ ef,
    const int* __restrict__ src, const int* __restrict__ dst,
    const float* __restrict__ wA, const float* __restrict__ bA,
    const float* __restrict__ wB, const float* __restrict__ bB,
    const float* __restrict__ wU, const float* __restrict__ bU,
    const u16* __restrict__ left, const u16* __restrict__ right,
    float* __restrict__ edge_node_acc,
    float* __restrict__ out_edge)
{
    __shared__ __align__(16) u16 sint[64 * 192];   // 24576 B
    __shared__ __align__(16) u16 buf [64 * 192];   // 24576 B (time-multiplexed)
    __shared__ float sb[3 * HH];                   // 600 B
    __shared__ int ssrc[64], sdst[64];             // 512 B   total ~50.3 KB

    const int tid = threadIdx.x;
    const int e0  = blockIdx.x * 64;               // E_N = 64 * 25000 exactly

    // ---- staging (phase 0) ----
    // zero sint fully (pads must be finite: NaN*0 = NaN)
    {
        uint4 z = make_uint4(0,0,0,0);
        for (int i = tid; i < 64*192/8; i += 256) ((uint4*)sint)[i] = z;
    }
    // wAt = w_e2n^T, wBt = w_e2e^T, padded+swizzled, full coverage
    for (int i = tid; i < 4096; i += 256) {
        const int c = i >> 6, ko = i & 63;
        const int o = (c << 6) + swz(c, ko);
        buf[o]        = (c < 50 && ko < 50) ? f2bf(wA[ko*50 + c]) : (u16)0;
        buf[4096 + o] = (c < 50 && ko < 50) ? f2bf(wB[ko*50 + c]) : (u16)0;
    }
    // sef = ef tile, bf16, padded+swizzled
    for (int i = tid; i < 4096; i += 256) {
        const int e = i >> 6, k = i & 63;
        buf[8192 + (e << 6) + swz(e, k)] =
            (k < 50) ? f2bf(ef[(size_t)(e0 + e)*50 + k]) : (u16)0;
    }
    for (int t = tid; t < 3*HH; t += 256)
        sb[t] = (t < 50) ? bA[t] : (t < 100 ? bB[t-50] : bU[t-100]);
    if (tid < 64) { ssrc[tid] = src[e0+tid]; sdst[tid] = dst[e0+tid]; }
    __syncthreads();

    const int lane = tid & 63, wv = tid >> 6;
    const int frow = lane & 15;
    const int kofs = (lane >> 4) << 3;             // 0,8,16,24
    const int rbase = wv*16 + ((lane >> 4) << 2);  // C rows: rbase + r

    // ---- gather: first/second -> sint (sections 0, 64) ----
    for (int t = tid; t < 16 * HH; t += 256) {
        const int et = t / HH, c = t - et * HH;
        const int e = et * 4;
        #pragma unroll
        for (int j = 0; j < 4; ++j) {
            const int s = ssrc[e+j], d = sdst[e+j];
            const float ls  = bf2f(left [(size_t)s*HH + c]);
            const float rd_ = bf2f(right[(size_t)d*HH + c]);
            const float rs  = bf2f(right[(size_t)s*HH + c]);
            const float ld  = bf2f(left [(size_t)d*HH + c]);
            sint[(e+j)*192 + swz(e+j, c)]      = f2bf(fmaxf(ls + rd_, 0.f));
            sint[(e+j)*192 + swz(e+j, 64 + c)] = f2bf(fmaxf(rs + ld,  0.f));
        }
    }

    // ---- stage 1: MFMA  e2n (atomics) + third (-> sint section 128) ----
    {
        const u16* wAt  = buf;
        const u16* wBt  = buf + 4096;
        const u16* sefp = buf + 8192;
        f32x4 zf = {0.f, 0.f, 0.f, 0.f};
        f32x4 accA[4], accB[4];
        #pragma unroll
        for (int nt = 0; nt < 4; ++nt) { accA[nt] = zf; accB[nt] = zf; }
        #pragma unroll
        for (int kt = 0; kt < 2; ++kt) {
            const int arow = wv*16 + frow;
            bf16x8 a = *(const bf16x8*)&sefp[(arow << 6) + swz(arow, kt*32 + kofs)];
            #pragma unroll
            for (int nt = 0; nt < 4; ++nt) {
                const int nrow = nt*16 + frow;
                bf16x8 b1 = *(const bf16x8*)&wAt[(nrow << 6) + swz(nrow, kt*32 + kofs)];
                bf16x8 b2 = *(const bf16x8*)&wBt[(nrow << 6) + swz(nrow, kt*32 + kofs)];
                accA[nt] = __builtin_amdgcn_mfma_f32_16x16x32_bf16(a, b1, accA[nt], 0, 0, 0);
                accB[nt] = __builtin_amdgcn_mfma_f32_16x16x32_bf16(a, b2, accB[nt], 0, 0, 0);
            }
        }
        #pragma unroll
        for (int nt = 0; nt < 4; ++nt) {
            const int c = nt*16 + frow;
            if (c < 50) {
                const float ba = sb[c], bb = sb[HH + c];
                #pragma unroll
                for (int r = 0; r < 4; ++r) {
                    const int row = rbase + r;
                    const float v1 = fmaxf(accA[nt][r] + ba, 0.f);
                    atomicAdd(&edge_node_acc[(size_t)sdst[row]*HH + c], v1);
                    sint[row*192 + swz(row, 128 + c)] =
                        f2bf(fmaxf(accB[nt][r] + bb, 0.f));
                }
            }
        }
    }
    __syncthreads();

    // ---- restage buf as swUt = w_upd_e^T [64][192], padded+swizzled ----
    for (int i = tid; i < 64*192; i += 256) {
        const int c = i / 192, kk = i - c*192;
        const int sec = kk >> 6, ko = kk & 63;
        u16 v = 0;
        if (c < 50 && ko < 50) v = f2bf(wU[(sec*50 + ko)*50 + c]);
        buf[c*192 + swz(c, kk)] = v;
    }
    __syncthreads();

    // ---- stage 2: MFMA  new_edge = relu(sint @ swUt + bU) ----
    {
        f32x4 zf = {0.f, 0.f, 0.f, 0.f};
        f32x4 acc[4];
        #pragma unroll
        for (int nt = 0; nt < 4; ++nt) acc[nt] = zf;
        #pragma unroll
        for (int kt = 0; kt < 6; ++kt) {
            const int arow = wv*16 + frow;
            bf16x8 a = *(const bf16x8*)&sint[arow*192 + swz(arow, kt*32 + kofs)];
            #pragma unroll
            for (int nt = 0; nt < 4; ++nt) {
                const int nrow = nt*16 + frow;
                bf16x8 b = *(const bf16x8*)&buf[nrow*192 + swz(nrow, kt*32 + kofs)];
                acc[nt] = __builtin_amdgcn_mfma_f32_16x16x32_bf16(a, b, acc[nt], 0, 0, 0);
            }
        }
        #pragma unroll
        for (int nt = 0; nt < 4; ++nt) {
            const int c = nt*16 + frow;
            if (c < 50) {
                const float bu = sb[2*HH + c];
                #pragma unroll
                for (int r = 0; r < 4; ++r) {
                    const int row = rbase + r;
                    out_edge[(size_t)(e0 + row)*HH + c] = fmaxf(acc[nt][r] + bu, 0.f);
                }
            }
        }
    }
}

// ---------------------------------------------------------------------------
// Kernel C: node update (unchanged — known-correct; ~150 us est., next target)
// ---------------------------------------------------------------------------
__global__ __launch_bounds__(256) void k_node_upd(
    const float* __restrict__ nf,
    const float* __restrict__ w_n2n, const float* __restrict__ b_n2n,
    const float* __restrict__ wU, const float* __restrict__ bU,
    float* __restrict__ node_out /* also edge_node accumulator */)
{
    __shared__ u16 swn[NIN*HH];
    __shared__ u16 swu[2*HH*HH];
    __shared__ float sb[2*HH];
    __shared__ u16 sx[64*NIN];
    __shared__ u16 snn[64*HH];
    __shared__ float sen[64*HH];

    const int tid = threadIdx.x;
    for (int i = tid; i < NIN*HH; i += 256) swn[i] = f2bf(w_n2n[i]);
    for (int i = tid; i < 2*HH*HH; i += 256) swu[i] = f2bf(wU[i]);
    if (tid < HH) { sb[tid] = b_n2n[tid]; sb[HH + tid] = bU[tid]; }

    const int n0 = blockIdx.x * 64;
    const float4* nf4 = (const float4*)nf;
    const int base4 = n0 * (NIN / 4);
    for (int i = tid; i < 64 * NIN / 4; i += 256) {
        float4 v = make_float4(0.f, 0.f, 0.f, 0.f);
        if (base4 + i < V_N * NIN / 4) v = nf4[base4 + i];
        ushort4 p;
        p.x = f2bf(v.x); p.y = f2bf(v.y); p.z = f2bf(v.z); p.w = f2bf(v.w);
        ((ushort4*)sx)[i] = p;
    }
    for (int i = tid; i < 64*HH; i += 256) {
        const int gi = n0*HH + i;
        sen[i] = (gi < V_N*HH) ? node_out[gi] : 0.f;
    }
    __syncthreads();

    for (int t = tid; t < 8 * HH; t += 256) {
        const int rt = t / HH, c = t - rt * HH;
        float a[8];
        #pragma unroll
        for (int j = 0; j < 8; ++j) a[j] = sb[c];
        const u16* xr = &sx[rt * 8 * NIN];
        for (int k = 0; k < NIN; ++k) {
            const float w = bf2f(swn[k*HH + c]);
            #pragma unroll
            for (int j = 0; j < 8; ++j) a[j] = fmaf(bf2f(xr[j*NIN + k]), w, a[j]);
        }
        #pragma unroll
        for (int j = 0; j < 8; ++j)
            snn[(rt*8 + j)*HH + c] = f2bf(fmaxf(a[j], 0.f));
    }
    __syncthreads();

    for (int t = tid; t < 16 * HH; t += 256) {
        const int et = t / HH, c = t - et * HH;
        const int n = et * 4;
        float acc[4];
        #pragma unroll
        for (int j = 0; j < 4; ++j) acc[j] = sb[HH + c];
        for (int k = 0; k < HH; ++k) {
            const float w = bf2f(swu[k*HH + c]);
            #pragma unroll
            for (int j = 0; j < 4; ++j) acc[j] = fmaf(bf2f(snn[(n+j)*HH + k]), w, acc[j]);
        }
        for (int k = 0; k < HH; ++k) {
            const float w = bf2f(swu[(HH + k)*HH + c]);
            #pragma unroll
            for (int j = 0; j < 4; ++j) acc[j] = fmaf(sen[(n+j)*HH + k], w, acc[j]);
        }
        #pragma unroll
        for (int j = 0; j < 4; ++j) {
            const int r = n0 + n + j;
            if (r < V_N) node_out[(size_t)r*HH + c] = fmaxf(acc[j], 0.f);
        }
    }
}

extern "C" void kernel_launch(void* const* d_in, const int* in_sizes, int n_in,
                              void* d_out, int out_size, void* d_ws, size_t ws_size,
                              hipStream_t stream) {
    const float* nf    = (const float*)d_in[0];
    const float* ef    = (const float*)d_in[1];
    const int*   src   = (const int*)d_in[2];
    const int*   dst   = (const int*)d_in[3];
    const float* w_n2n = (const float*)d_in[4];  const float* b_n2n = (const float*)d_in[5];
    const float* w_e2n = (const float*)d_in[6];  const float* b_e2n = (const float*)d_in[7];
    const float* w_updn= (const float*)d_in[8];  const float* b_updn= (const float*)d_in[9];
    const float* w_l   = (const float*)d_in[10]; const float* b_l   = (const float*)d_in[11];
    const float* w_r   = (const float*)d_in[12]; const float* b_r   = (const float*)d_in[13];
    const float* w_e2e = (const float*)d_in[14]; const float* b_e2e = (const float*)d_in[15];
    const float* w_upde= (const float*)d_in[16]; const float* b_upde= (const float*)d_in[17];

    // workspace layout: [0,10MB) left bf16 (V x 50), [10,20MB) right bf16
    char* ws = (char*)d_ws;
    u16* left  = (u16*)ws;
    u16* right = (u16*)(ws + 10000000);

    float* out_node = (float*)d_out;   // doubles as edge_node fp32 accumulator
    float* out_edge = out_node + (size_t)V_N * HH;

    hipMemsetAsync(out_node, 0, (size_t)V_N * HH * sizeof(float), stream);

    k_lr<<<(V_N + 63)/64, 256, 0, stream>>>(nf, w_l, b_l, w_r, b_r, left, right);

    k_edge<<<E_N/64, 256, 0, stream>>>(
        ef, src, dst, w_e2n, b_e2n, w_e2e, b_e2e, w_upde, b_upde,
        left, right, out_node, out_edge);

    k_node_upd<<<(V_N + 63)/64, 256, 0, stream>>>(
        nf, w_n2n, b_n2n, w_updn, b_updn, out_node);
}

// Round 5
// 1416.675 us; speedup vs baseline: 1.4208x; 1.4208x over previous
//
#include <hip/hip_runtime.h>
#include <hip/hip_bf16.h>

typedef unsigned short u16;
typedef unsigned int   u32;

#define V_N 100000
#define E_N 1600000
#define NIN 128
#define EIN 50
#define HH  50
#define TPB 8   // 64-edge tiles per block in k_edge; E_N = 3125 * 8 * 64 exactly

typedef __attribute__((ext_vector_type(8))) short bf16x8;
typedef __attribute__((ext_vector_type(4))) float f32x4;

__device__ __forceinline__ float bf2f(u16 u) {
    union { u32 i; float f; } v; v.i = ((u32)u) << 16; return v.f;
}
__device__ __forceinline__ u16 f2bf(float f) {
    union { float f; u32 i; } v; v.f = f;
    u32 x = v.i;
    return (u16)((x + 0x7fffu + ((x >> 16) & 1u)) >> 16);
}
// XOR swizzle: flips bits 3..5 of the element-in-row index (16B granules within
// each 128B sub-block). Breaks the 16-way bank conflict of stride-384B rows.
// Measured working: SQ_LDS_BANK_CONFLICT ~120/block in round-3 profile.
__device__ __forceinline__ int swz(int row, int k) { return k ^ ((row & 7) << 3); }

// ---------------------------------------------------------------------------
// Kernel A: left = nf @ w_l + b_l, right = nf @ w_r + b_r  (bf16 out to ws)
// (unchanged — known-correct)
// ---------------------------------------------------------------------------
__global__ __launch_bounds__(256) void k_lr(
    const float* __restrict__ nf,
    const float* __restrict__ w1, const float* __restrict__ b1,
    const float* __restrict__ w2, const float* __restrict__ b2,
    u16* __restrict__ left, u16* __restrict__ right)
{
    __shared__ u16 sw[2 * NIN * HH];
    __shared__ u16 sx[64 * NIN];
    __shared__ float sb[2 * HH];

    const int tid = threadIdx.x;
    for (int i = tid; i < NIN * HH; i += 256) {
        sw[i]          = f2bf(w1[i]);
        sw[NIN*HH + i] = f2bf(w2[i]);
    }
    if (tid < HH) {
        sb[tid]      = b1[tid];
        sb[HH + tid] = b2[tid];
    }
    const int row0 = blockIdx.x * 64;
    const float4* nf4 = (const float4*)nf;
    const int base4 = row0 * (NIN / 4);
    for (int i = tid; i < 64 * NIN / 4; i += 256) {
        float4 v = make_float4(0.f, 0.f, 0.f, 0.f);
        if (base4 + i < V_N * NIN / 4) v = nf4[base4 + i];
        ushort4 p;
        p.x = f2bf(v.x); p.y = f2bf(v.y); p.z = f2bf(v.z); p.w = f2bf(v.w);
        ((ushort4*)sx)[i] = p;
    }
    __syncthreads();

    for (int t = tid; t < 8 * HH; t += 256) {
        const int rt = t / HH, c = t - rt * HH;
        float a1[8], a2[8];
        #pragma unroll
        for (int j = 0; j < 8; ++j) { a1[j] = sb[c]; a2[j] = sb[HH+c]; }
        const u16* xr = &sx[rt * 8 * NIN];
        for (int k = 0; k < NIN; ++k) {
            const float wv1 = bf2f(sw[k*HH + c]);
            const float wv2 = bf2f(sw[NIN*HH + k*HH + c]);
            #pragma unroll
            for (int j = 0; j < 8; ++j) {
                const float x = bf2f(xr[j*NIN + k]);
                a1[j] = fmaf(x, wv1, a1[j]);
                a2[j] = fmaf(x, wv2, a2[j]);
            }
        }
        #pragma unroll
        for (int j = 0; j < 8; ++j) {
            const int r = row0 + rt*8 + j;
            if (r < V_N) {
                left [(size_t)r*HH + c] = f2bf(a1[j]);
                right[(size_t)r*HH + c] = f2bf(a2[j]);
            }
        }
    }
}

// ---------------------------------------------------------------------------
// Kernel B v2: 8 tiles of 64 edges per block; weights staged ONCE per block.
//   - wU^T in LDS [64][192] swizzled (staged once; was restaged per 64 edges)
//   - wA^T/wB^T as per-lane register B-fragments (64 VGPRs, loaded once)
//   - stage-1 A-fragments loaded directly from global ef (guarded float2),
//     sef LDS buffer eliminated
//   - gather vectorized ushort2 (rows 4B-aligned)
//   - sint zeroed once per block: pads never rewritten; all live elements
//     (k' 0..49, 64..113 by gather; 128..177 by stage-1 epilogue) rewritten
//     every tile, and pad columns multiply zero wU^T rows.
//   - 2 barriers per tile (was 4): ssrc reload overlaps previous stage-2.
// LDS: sint 24576 + wUt 24576 + sb 600 + ssrc/sdst 512 = 50264 B -> 3 blk/CU.
// ---------------------------------------------------------------------------
__global__ __launch_bounds__(256, 3) void k_edge(
    const float* __restrict__ ef,
    const int* __restrict__ src, const int* __restrict__ dst,
    const float* __restrict__ wA, const float* __restrict__ bA,
    const float* __restrict__ wB, const float* __restrict__ bB,
    const float* __restrict__ wU, const float* __restrict__ bU,
    const u16* __restrict__ left, const u16* __restrict__ right,
    float* __restrict__ edge_node_acc,
    float* __restrict__ out_edge)
{
    __shared__ __align__(16) u16 sint[64 * 192];   // 24576 B
    __shared__ __align__(16) u16 wUt [64 * 192];   // 24576 B
    __shared__ float sb[3 * HH];                   // 600 B
    __shared__ int ssrc[64], sdst[64];             // 512 B

    const int tid  = threadIdx.x;
    const int lane = tid & 63, wv = tid >> 6;
    const int frow = lane & 15;
    const int kofs = (lane >> 4) << 3;             // 0,8,16,24
    const int rbase = wv*16 + ((lane >> 4) << 2);  // C rows: rbase + r
    const int arow  = wv*16 + frow;                // A row (edge-local)

    // ---- block-start staging (once) ----
    {
        uint4 z = make_uint4(0,0,0,0);
        for (int i = tid; i < 64*192/8; i += 256) ((uint4*)sint)[i] = z;
    }
    for (int i = tid; i < 64*192; i += 256) {
        const int c = i / 192, kk = i - c*192;
        const int sec = kk >> 6, ko = kk & 63;
        u16 v = 0;
        if (c < 50 && ko < 50) v = f2bf(wU[(sec*50 + ko)*50 + c]);
        wUt[c*192 + swz(c, kk)] = v;
    }
    if (tid < 3*HH)
        sb[tid] = (tid < 50) ? bA[tid] : (tid < 100 ? bB[tid-50] : bU[tid-100]);

    // register B-fragments for stage 1 (W^T[n][k], n=nt*16+frow, k=kt*32+kofs+j)
    bf16x8 bAf[2][4], bBf[2][4];
    #pragma unroll
    for (int kt = 0; kt < 2; ++kt) {
        #pragma unroll
        for (int nt = 0; nt < 4; ++nt) {
            union { bf16x8 v; u16 u[8]; } r1, r2;
            const int n = nt*16 + frow;
            #pragma unroll
            for (int j = 0; j < 8; ++j) {
                const int k = kt*32 + kofs + j;
                float v1 = 0.f, v2 = 0.f;
                if (k < 50 && n < 50) { v1 = wA[k*50 + n]; v2 = wB[k*50 + n]; }
                r1.u[j] = f2bf(v1); r2.u[j] = f2bf(v2);
            }
            bAf[kt][nt] = r1.v; bBf[kt][nt] = r2.v;
        }
    }
    __syncthreads();

    for (int tile = 0; tile < TPB; ++tile) {
        const int e0t = blockIdx.x * (64*TPB) + tile*64;

        // ssrc/sdst reload: safe concurrent with previous tile's stage-2
        // (stage-2 touches only sint/wUt/out_edge).
        if (tid < 64) { ssrc[tid] = src[e0t+tid]; sdst[tid] = dst[e0t+tid]; }
        __syncthreads();   // (a) prev stage-2 done reading sint; ssrc visible

        // ---- gather: first/second -> sint sections 0, 64 (ushort2) ----
        for (int t = tid; t < 64*25; t += 256) {
            const int e = t / 25, q = t - e*25, c = q*2;
            const int s = ssrc[e], d = sdst[e];
            const ushort2 ls  = *(const ushort2*)&left [(size_t)s*HH + c];
            const ushort2 rd_ = *(const ushort2*)&right[(size_t)d*HH + c];
            const ushort2 rs  = *(const ushort2*)&right[(size_t)s*HH + c];
            const ushort2 ld  = *(const ushort2*)&left [(size_t)d*HH + c];
            const u32 p1 = (u32)f2bf(fmaxf(bf2f(ls.x) + bf2f(rd_.x), 0.f))
                         | ((u32)f2bf(fmaxf(bf2f(ls.y) + bf2f(rd_.y), 0.f)) << 16);
            const u32 p2 = (u32)f2bf(fmaxf(bf2f(rs.x) + bf2f(ld.x), 0.f))
                         | ((u32)f2bf(fmaxf(bf2f(rs.y) + bf2f(ld.y), 0.f)) << 16);
            *(u32*)&sint[e*192 + swz(e, c)]      = p1;
            *(u32*)&sint[e*192 + swz(e, 64 + c)] = p2;
        }

        // ---- stage 1: e2n (atomics) + third (-> sint section 128) ----
        {
            f32x4 zf = {0.f, 0.f, 0.f, 0.f};
            f32x4 accA[4], accB[4];
            #pragma unroll
            for (int nt = 0; nt < 4; ++nt) { accA[nt] = zf; accB[nt] = zf; }
            const float* efr = ef + (size_t)(e0t + arow) * EIN;
            #pragma unroll
            for (int kt = 0; kt < 2; ++kt) {
                union { bf16x8 v; u16 u[8]; } a;
                #pragma unroll
                for (int p = 0; p < 4; ++p) {
                    const int k = kt*32 + kofs + 2*p;
                    float2 f = make_float2(0.f, 0.f);
                    if (k < 50) f = *(const float2*)&efr[k];   // exec-masked, 8B-aligned
                    a.u[2*p]   = f2bf(f.x);
                    a.u[2*p+1] = f2bf(f.y);
                }
                #pragma unroll
                for (int nt = 0; nt < 4; ++nt) {
                    accA[nt] = __builtin_amdgcn_mfma_f32_16x16x32_bf16(a.v, bAf[kt][nt], accA[nt], 0, 0, 0);
                    accB[nt] = __builtin_amdgcn_mfma_f32_16x16x32_bf16(a.v, bBf[kt][nt], accB[nt], 0, 0, 0);
                }
            }
            #pragma unroll
            for (int nt = 0; nt < 4; ++nt) {
                const int c = nt*16 + frow;
                if (c < 50) {
                    const float ba = sb[c], bb = sb[HH + c];
                    #pragma unroll
                    for (int r = 0; r < 4; ++r) {
                        const int row = rbase + r;
                        const float v1 = fmaxf(accA[nt][r] + ba, 0.f);
                        atomicAdd(&edge_node_acc[(size_t)sdst[row]*HH + c], v1);
                        sint[row*192 + swz(row, 128 + c)] =
                            f2bf(fmaxf(accB[nt][r] + bb, 0.f));
                    }
                }
            }
        }
        __syncthreads();   // (b) sint fully written

        // ---- stage 2: new_edge = relu(sint @ wUt + bU) ----
        {
            f32x4 zf = {0.f, 0.f, 0.f, 0.f};
            f32x4 acc[4];
            #pragma unroll
            for (int nt = 0; nt < 4; ++nt) acc[nt] = zf;
            #pragma unroll
            for (int kt = 0; kt < 6; ++kt) {
                bf16x8 a = *(const bf16x8*)&sint[arow*192 + swz(arow, kt*32 + kofs)];
                #pragma unroll
                for (int nt = 0; nt < 4; ++nt) {
                    const int nrow = nt*16 + frow;
                    bf16x8 b = *(const bf16x8*)&wUt[nrow*192 + swz(nrow, kt*32 + kofs)];
                    acc[nt] = __builtin_amdgcn_mfma_f32_16x16x32_bf16(a, b, acc[nt], 0, 0, 0);
                }
            }
            #pragma unroll
            for (int nt = 0; nt < 4; ++nt) {
                const int c = nt*16 + frow;
                if (c < 50) {
                    const float bu = sb[2*HH + c];
                    #pragma unroll
                    for (int r = 0; r < 4; ++r) {
                        const int row = rbase + r;
                        out_edge[(size_t)(e0t + row)*HH + c] = fmaxf(acc[nt][r] + bu, 0.f);
                    }
                }
            }
        }
    }
}

// ---------------------------------------------------------------------------
// Kernel C: node update (unchanged — known-correct)
// ---------------------------------------------------------------------------
__global__ __launch_bounds__(256) void k_node_upd(
    const float* __restrict__ nf,
    const float* __restrict__ w_n2n, const float* __restrict__ b_n2n,
    const float* __restrict__ wU, const float* __restrict__ bU,
    float* __restrict__ node_out /* also edge_node accumulator */)
{
    __shared__ u16 swn[NIN*HH];
    __shared__ u16 swu[2*HH*HH];
    __shared__ float sb[2*HH];
    __shared__ u16 sx[64*NIN];
    __shared__ u16 snn[64*HH];
    __shared__ float sen[64*HH];

    const int tid = threadIdx.x;
    for (int i = tid; i < NIN*HH; i += 256) swn[i] = f2bf(w_n2n[i]);
    for (int i = tid; i < 2*HH*HH; i += 256) swu[i] = f2bf(wU[i]);
    if (tid < HH) { sb[tid] = b_n2n[tid]; sb[HH + tid] = bU[tid]; }

    const int n0 = blockIdx.x * 64;
    const float4* nf4 = (const float4*)nf;
    const int base4 = n0 * (NIN / 4);
    for (int i = tid; i < 64 * NIN / 4; i += 256) {
        float4 v = make_float4(0.f, 0.f, 0.f, 0.f);
        if (base4 + i < V_N * NIN / 4) v = nf4[base4 + i];
        ushort4 p;
        p.x = f2bf(v.x); p.y = f2bf(v.y); p.z = f2bf(v.z); p.w = f2bf(v.w);
        ((ushort4*)sx)[i] = p;
    }
    for (int i = tid; i < 64*HH; i += 256) {
        const int gi = n0*HH + i;
        sen[i] = (gi < V_N*HH) ? node_out[gi] : 0.f;
    }
    __syncthreads();

    for (int t = tid; t < 8 * HH; t += 256) {
        const int rt = t / HH, c = t - rt * HH;
        float a[8];
        #pragma unroll
        for (int j = 0; j < 8; ++j) a[j] = sb[c];
        const u16* xr = &sx[rt * 8 * NIN];
        for (int k = 0; k < NIN; ++k) {
            const float w = bf2f(swn[k*HH + c]);
            #pragma unroll
            for (int j = 0; j < 8; ++j) a[j] = fmaf(bf2f(xr[j*NIN + k]), w, a[j]);
        }
        #pragma unroll
        for (int j = 0; j < 8; ++j)
            snn[(rt*8 + j)*HH + c] = f2bf(fmaxf(a[j], 0.f));
    }
    __syncthreads();

    for (int t = tid; t < 16 * HH; t += 256) {
        const int et = t / HH, c = t - et * HH;
        const int n = et * 4;
        float acc[4];
        #pragma unroll
        for (int j = 0; j < 4; ++j) acc[j] = sb[HH + c];
        for (int k = 0; k < HH; ++k) {
            const float w = bf2f(swu[k*HH + c]);
            #pragma unroll
            for (int j = 0; j < 4; ++j) acc[j] = fmaf(bf2f(snn[(n+j)*HH + k]), w, acc[j]);
        }
        for (int k = 0; k < HH; ++k) {
            const float w = bf2f(swu[(HH + k)*HH + c]);
            #pragma unroll
            for (int j = 0; j < 4; ++j) acc[j] = fmaf(sen[(n+j)*HH + k], w, acc[j]);
        }
        #pragma unroll
        for (int j = 0; j < 4; ++j) {
            const int r = n0 + n + j;
            if (r < V_N) node_out[(size_t)r*HH + c] = fmaxf(acc[j], 0.f);
        }
    }
}

extern "C" void kernel_launch(void* const* d_in, const int* in_sizes, int n_in,
                              void* d_out, int out_size, void* d_ws, size_t ws_size,
                              hipStream_t stream) {
    const float* nf    = (const float*)d_in[0];
    const float* ef    = (const float*)d_in[1];
    const int*   src   = (const int*)d_in[2];
    const int*   dst   = (const int*)d_in[3];
    const float* w_n2n = (const float*)d_in[4];  const float* b_n2n = (const float*)d_in[5];
    const float* w_e2n = (const float*)d_in[6];  const float* b_e2n = (const float*)d_in[7];
    const float* w_updn= (const float*)d_in[8];  const float* b_updn= (const float*)d_in[9];
    const float* w_l   = (const float*)d_in[10]; const float* b_l   = (const float*)d_in[11];
    const float* w_r   = (const float*)d_in[12]; const float* b_r   = (const float*)d_in[13];
    const float* w_e2e = (const float*)d_in[14]; const float* b_e2e = (const float*)d_in[15];
    const float* w_upde= (const float*)d_in[16]; const float* b_upde= (const float*)d_in[17];

    // workspace layout: [0,10MB) left bf16 (V x 50), [10,20MB) right bf16
    char* ws = (char*)d_ws;
    u16* left  = (u16*)ws;
    u16* right = (u16*)(ws + 10000000);

    float* out_node = (float*)d_out;   // doubles as edge_node fp32 accumulator
    float* out_edge = out_node + (size_t)V_N * HH;

    hipMemsetAsync(out_node, 0, (size_t)V_N * HH * sizeof(float), stream);

    k_lr<<<(V_N + 63)/64, 256, 0, stream>>>(nf, w_l, b_l, w_r, b_r, left, right);

    k_edge<<<E_N/(64*TPB), 256, 0, stream>>>(
        ef, src, dst, w_e2n, b_e2n, w_e2e, b_e2e, w_upde, b_upde,
        left, right, out_node, out_edge);

    k_node_upd<<<(V_N + 63)/64, 256, 0, stream>>>(
        nf, w_n2n, b_n2n, w_updn, b_updn, out_node);
}

// Round 6
// 1275.159 us; speedup vs baseline: 1.5785x; 1.1110x over previous
//
#include <hip/hip_runtime.h>
#include <hip/hip_bf16.h>

typedef unsigned short u16;
typedef unsigned int   u32;

#define V_N 100000
#define E_N 1600000
#define NIN 128
#define EIN 50
#define HH  50
#define TPB 8   // 64-edge tiles per block in k_edge; E_N = 3125 * 8 * 64 exactly

typedef __attribute__((ext_vector_type(8))) short bf16x8;
typedef __attribute__((ext_vector_type(4))) float f32x4;

__device__ __forceinline__ float bf2f(u16 u) {
    union { u32 i; float f; } v; v.i = ((u32)u) << 16; return v.f;
}
__device__ __forceinline__ u16 f2bf(float f) {
    union { float f; u32 i; } v; v.f = f;
    u32 x = v.i;
    return (u16)((x + 0x7fffu + ((x >> 16) & 1u)) >> 16);
}
// XOR swizzle on the element-in-row index (8-element/16B granules within each
// 128B sub-block). Verified on HW: k_edge SQ_LDS_BANK_CONFLICT ~800/block.
__device__ __forceinline__ int swz(int row, int k) { return k ^ ((row & 7) << 3); }

// ---------------------------------------------------------------------------
// Kernel A v2 (MFMA): C[64][112] = nf_tile[64][128] @ [w_l | w_r | 0]^T.
// cols 0..49 -> left, 50..99 -> right (both bf16, NO relu — consumed by k_edge).
// LDS: sxa 16384 + swt 28672 + sb 448 = 45504 B -> 3 blocks/CU.
// ---------------------------------------------------------------------------
__global__ __launch_bounds__(256, 3) void k_lr(
    const float* __restrict__ nf,
    const float* __restrict__ w1, const float* __restrict__ b1,
    const float* __restrict__ w2, const float* __restrict__ b2,
    u16* __restrict__ left, u16* __restrict__ right)
{
    __shared__ __align__(16) u16 sxa[64 * 128];    // nf tile, bf16, swizzled
    __shared__ __align__(16) u16 swt[112 * 128];   // [w_l|w_r]^T, bf16, swizzled
    __shared__ float sb[112];

    const int tid  = threadIdx.x;
    const int row0 = blockIdx.x * 64;

    // stage nf tile (guarded rows), float4 -> ushort4, swizzled (4-aligned ok:
    // swz flips bits 3..5 only, so 4-element chunks stay contiguous)
    const float4* nf4 = (const float4*)nf;
    for (int i = tid; i < 64 * 32; i += 256) {
        const int row = i >> 5, k4 = (i & 31) << 2;
        float4 v = make_float4(0.f, 0.f, 0.f, 0.f);
        const int gr = row0 + row;
        if (gr < V_N) v = nf4[(size_t)gr * 32 + (k4 >> 2)];
        ushort4 p;
        p.x = f2bf(v.x); p.y = f2bf(v.y); p.z = f2bf(v.z); p.w = f2bf(v.w);
        *(ushort4*)&sxa[(row << 7) + swz(row, k4)] = p;
    }
    // stage W^T [n][k]: n<50 -> w_l col n, n<100 -> w_r col n-50, else 0
    for (int i = tid; i < 112 * 128; i += 256) {
        const int n = i >> 7, k = i & 127;
        float v = 0.f;
        if (n < 50)       v = w1[k*50 + n];
        else if (n < 100) v = w2[k*50 + (n - 50)];
        swt[(n << 7) + swz(n, k)] = f2bf(v);
    }
    if (tid < 112)
        sb[tid] = (tid < 50) ? b1[tid] : (tid < 100 ? b2[tid - 50] : 0.f);
    __syncthreads();

    const int lane = tid & 63, wv = tid >> 6;
    const int frow = lane & 15;
    const int kofs = (lane >> 4) << 3;
    const int rbase = wv*16 + ((lane >> 4) << 2);
    const int arow  = wv*16 + frow;

    f32x4 zf = {0.f, 0.f, 0.f, 0.f};
    f32x4 acc[7];
    #pragma unroll
    for (int nt = 0; nt < 7; ++nt) acc[nt] = zf;

    #pragma unroll
    for (int kt = 0; kt < 4; ++kt) {
        bf16x8 a = *(const bf16x8*)&sxa[(arow << 7) + swz(arow, kt*32 + kofs)];
        #pragma unroll
        for (int nt = 0; nt < 7; ++nt) {
            const int nrow = nt*16 + frow;
            bf16x8 b = *(const bf16x8*)&swt[(nrow << 7) + swz(nrow, kt*32 + kofs)];
            acc[nt] = __builtin_amdgcn_mfma_f32_16x16x32_bf16(a, b, acc[nt], 0, 0, 0);
        }
    }
    #pragma unroll
    for (int nt = 0; nt < 7; ++nt) {
        const int g = nt*16 + frow;
        if (g < 100) {
            const float bias = sb[g];
            #pragma unroll
            for (int r = 0; r < 4; ++r) {
                const int gr = row0 + rbase + r;
                if (gr < V_N) {
                    const u16 o = f2bf(acc[nt][r] + bias);
                    if (g < 50) left [(size_t)gr*HH + g]      = o;
                    else        right[(size_t)gr*HH + g - 50] = o;
                }
            }
        }
    }
}

// ---------------------------------------------------------------------------
// Kernel B v2: UNCHANGED from round-5 verified version (685.8 us, passed).
// ---------------------------------------------------------------------------
__global__ __launch_bounds__(256, 3) void k_edge(
    const float* __restrict__ ef,
    const int* __restrict__ src, const int* __restrict__ dst,
    const float* __restrict__ wA, const float* __restrict__ bA,
    const float* __restrict__ wB, const float* __restrict__ bB,
    const float* __restrict__ wU, const float* __restrict__ bU,
    const u16* __restrict__ left, const u16* __restrict__ right,
    float* __restrict__ edge_node_acc,
    float* __restrict__ out_edge)
{
    __shared__ __align__(16) u16 sint[64 * 192];   // 24576 B
    __shared__ __align__(16) u16 wUt [64 * 192];   // 24576 B
    __shared__ float sb[3 * HH];                   // 600 B
    __shared__ int ssrc[64], sdst[64];             // 512 B

    const int tid  = threadIdx.x;
    const int lane = tid & 63, wv = tid >> 6;
    const int frow = lane & 15;
    const int kofs = (lane >> 4) << 3;             // 0,8,16,24
    const int rbase = wv*16 + ((lane >> 4) << 2);  // C rows: rbase + r
    const int arow  = wv*16 + frow;                // A row (edge-local)

    // ---- block-start staging (once) ----
    {
        uint4 z = make_uint4(0,0,0,0);
        for (int i = tid; i < 64*192/8; i += 256) ((uint4*)sint)[i] = z;
    }
    for (int i = tid; i < 64*192; i += 256) {
        const int c = i / 192, kk = i - c*192;
        const int sec = kk >> 6, ko = kk & 63;
        u16 v = 0;
        if (c < 50 && ko < 50) v = f2bf(wU[(sec*50 + ko)*50 + c]);
        wUt[c*192 + swz(c, kk)] = v;
    }
    if (tid < 3*HH)
        sb[tid] = (tid < 50) ? bA[tid] : (tid < 100 ? bB[tid-50] : bU[tid-100]);

    // register B-fragments for stage 1 (W^T[n][k], n=nt*16+frow, k=kt*32+kofs+j)
    bf16x8 bAf[2][4], bBf[2][4];
    #pragma unroll
    for (int kt = 0; kt < 2; ++kt) {
        #pragma unroll
        for (int nt = 0; nt < 4; ++nt) {
            union { bf16x8 v; u16 u[8]; } r1, r2;
            const int n = nt*16 + frow;
            #pragma unroll
            for (int j = 0; j < 8; ++j) {
                const int k = kt*32 + kofs + j;
                float v1 = 0.f, v2 = 0.f;
                if (k < 50 && n < 50) { v1 = wA[k*50 + n]; v2 = wB[k*50 + n]; }
                r1.u[j] = f2bf(v1); r2.u[j] = f2bf(v2);
            }
            bAf[kt][nt] = r1.v; bBf[kt][nt] = r2.v;
        }
    }
    __syncthreads();

    for (int tile = 0; tile < TPB; ++tile) {
        const int e0t = blockIdx.x * (64*TPB) + tile*64;

        if (tid < 64) { ssrc[tid] = src[e0t+tid]; sdst[tid] = dst[e0t+tid]; }
        __syncthreads();   // (a) prev stage-2 done reading sint; ssrc visible

        // ---- gather: first/second -> sint sections 0, 64 (ushort2) ----
        for (int t = tid; t < 64*25; t += 256) {
            const int e = t / 25, q = t - e*25, c = q*2;
            const int s = ssrc[e], d = sdst[e];
            const ushort2 ls  = *(const ushort2*)&left [(size_t)s*HH + c];
            const ushort2 rd_ = *(const ushort2*)&right[(size_t)d*HH + c];
            const ushort2 rs  = *(const ushort2*)&right[(size_t)s*HH + c];
            const ushort2 ld  = *(const ushort2*)&left [(size_t)d*HH + c];
            const u32 p1 = (u32)f2bf(fmaxf(bf2f(ls.x) + bf2f(rd_.x), 0.f))
                         | ((u32)f2bf(fmaxf(bf2f(ls.y) + bf2f(rd_.y), 0.f)) << 16);
            const u32 p2 = (u32)f2bf(fmaxf(bf2f(rs.x) + bf2f(ld.x), 0.f))
                         | ((u32)f2bf(fmaxf(bf2f(rs.y) + bf2f(ld.y), 0.f)) << 16);
            *(u32*)&sint[e*192 + swz(e, c)]      = p1;
            *(u32*)&sint[e*192 + swz(e, 64 + c)] = p2;
        }

        // ---- stage 1: e2n (atomics) + third (-> sint section 128) ----
        {
            f32x4 zf = {0.f, 0.f, 0.f, 0.f};
            f32x4 accA[4], accB[4];
            #pragma unroll
            for (int nt = 0; nt < 4; ++nt) { accA[nt] = zf; accB[nt] = zf; }
            const float* efr = ef + (size_t)(e0t + arow) * EIN;
            #pragma unroll
            for (int kt = 0; kt < 2; ++kt) {
                union { bf16x8 v; u16 u[8]; } a;
                #pragma unroll
                for (int p = 0; p < 4; ++p) {
                    const int k = kt*32 + kofs + 2*p;
                    float2 f = make_float2(0.f, 0.f);
                    if (k < 50) f = *(const float2*)&efr[k];   // exec-masked, 8B-aligned
                    a.u[2*p]   = f2bf(f.x);
                    a.u[2*p+1] = f2bf(f.y);
                }
                #pragma unroll
                for (int nt = 0; nt < 4; ++nt) {
                    accA[nt] = __builtin_amdgcn_mfma_f32_16x16x32_bf16(a.v, bAf[kt][nt], accA[nt], 0, 0, 0);
                    accB[nt] = __builtin_amdgcn_mfma_f32_16x16x32_bf16(a.v, bBf[kt][nt], accB[nt], 0, 0, 0);
                }
            }
            #pragma unroll
            for (int nt = 0; nt < 4; ++nt) {
                const int c = nt*16 + frow;
                if (c < 50) {
                    const float ba = sb[c], bb = sb[HH + c];
                    #pragma unroll
                    for (int r = 0; r < 4; ++r) {
                        const int row = rbase + r;
                        const float v1 = fmaxf(accA[nt][r] + ba, 0.f);
                        atomicAdd(&edge_node_acc[(size_t)sdst[row]*HH + c], v1);
                        sint[row*192 + swz(row, 128 + c)] =
                            f2bf(fmaxf(accB[nt][r] + bb, 0.f));
                    }
                }
            }
        }
        __syncthreads();   // (b) sint fully written

        // ---- stage 2: new_edge = relu(sint @ wUt + bU) ----
        {
            f32x4 zf = {0.f, 0.f, 0.f, 0.f};
            f32x4 acc[4];
            #pragma unroll
            for (int nt = 0; nt < 4; ++nt) acc[nt] = zf;
            #pragma unroll
            for (int kt = 0; kt < 6; ++kt) {
                bf16x8 a = *(const bf16x8*)&sint[arow*192 + swz(arow, kt*32 + kofs)];
                #pragma unroll
                for (int nt = 0; nt < 4; ++nt) {
                    const int nrow = nt*16 + frow;
                    bf16x8 b = *(const bf16x8*)&wUt[nrow*192 + swz(nrow, kt*32 + kofs)];
                    acc[nt] = __builtin_amdgcn_mfma_f32_16x16x32_bf16(a, b, acc[nt], 0, 0, 0);
                }
            }
            #pragma unroll
            for (int nt = 0; nt < 4; ++nt) {
                const int c = nt*16 + frow;
                if (c < 50) {
                    const float bu = sb[2*HH + c];
                    #pragma unroll
                    for (int r = 0; r < 4; ++r) {
                        const int row = rbase + r;
                        out_edge[(size_t)(e0t + row)*HH + c] = fmaxf(acc[nt][r] + bu, 0.f);
                    }
                }
            }
        }
    }
}

// ---------------------------------------------------------------------------
// Kernel C v2 (MFMA): phase B nn = relu(nf@w_n2n+b); phase C new_node =
// relu(concat @ w_upd_n + b) with K' = 192: k' 0..49 = nn (bf16),
// 50..99 = en_hi, 100..149 = en_lo (bf16 hi/lo split of the fp32 accumulator
// -> numerically equivalent to fp32 en, no precision regression), 150..191 = 0.
// swu rows: k'<100 -> wU[k'], 100..149 -> wU[k'-50], else 0.
// smem region: [0,8192) nf tile, [8192,16384) w_n2n^T during phase B;
// reused as concat[64][192] (12288 elems) after phase B.
// LDS: 32768 + 24576 + 512 = 57856 B -> 2 blocks/CU.
// ---------------------------------------------------------------------------
__global__ __launch_bounds__(256, 2) void k_node_upd(
    const float* __restrict__ nf,
    const float* __restrict__ w_n2n, const float* __restrict__ b_n2n,
    const float* __restrict__ wU, const float* __restrict__ bU,
    float* __restrict__ node_out /* also edge_node accumulator */)
{
    __shared__ __align__(16) u16 smem[64*128 + 64*128];  // 32768 B
    __shared__ __align__(16) u16 swu[64 * 192];          // 24576 B
    __shared__ float sb[128];                            // b_n2n@0, bU@64

    const int tid = threadIdx.x;
    const int n0  = blockIdx.x * 64;

    // ---- stage: nf tile (swizzled bf16) + w_n2n^T + wU^T(sectioned) ----
    const float4* nf4 = (const float4*)nf;
    for (int i = tid; i < 64 * 32; i += 256) {
        const int row = i >> 5, k4 = (i & 31) << 2;
        float4 v = make_float4(0.f, 0.f, 0.f, 0.f);
        const int gr = n0 + row;
        if (gr < V_N) v = nf4[(size_t)gr * 32 + (k4 >> 2)];
        ushort4 p;
        p.x = f2bf(v.x); p.y = f2bf(v.y); p.z = f2bf(v.z); p.w = f2bf(v.w);
        *(ushort4*)&smem[(row << 7) + swz(row, k4)] = p;
    }
    for (int i = tid; i < 64 * 128; i += 256) {
        const int n = i >> 7, k = i & 127;
        const float v = (n < 50) ? w_n2n[k*50 + n] : 0.f;
        smem[8192 + (n << 7) + swz(n, k)] = f2bf(v);
    }
    for (int i = tid; i < 64 * 192; i += 256) {
        const int n = i / 192, kk = i - n*192;
        float v = 0.f;
        if (n < 50) {
            if (kk < 100)      v = wU[kk*50 + n];
            else if (kk < 150) v = wU[(kk - 50)*50 + n];
        }
        swu[n*192 + swz(n, kk)] = f2bf(v);
    }
    if (tid < 128) {
        float v = 0.f;
        if (tid < 50) v = b_n2n[tid];
        else if (tid >= 64 && tid < 114) v = bU[tid - 64];
        sb[tid] = v;
    }
    __syncthreads();

    const int lane = tid & 63, wv = tid >> 6;
    const int frow = lane & 15;
    const int kofs = (lane >> 4) << 3;
    const int rbase = wv*16 + ((lane >> 4) << 2);
    const int arow  = wv*16 + frow;

    f32x4 zf = {0.f, 0.f, 0.f, 0.f};

    // ---- phase B: nn = nf @ w_n2n (bias+relu in epilogue) ----
    f32x4 accB[4];
    #pragma unroll
    for (int nt = 0; nt < 4; ++nt) accB[nt] = zf;
    #pragma unroll
    for (int kt = 0; kt < 4; ++kt) {
        bf16x8 a = *(const bf16x8*)&smem[(arow << 7) + swz(arow, kt*32 + kofs)];
        #pragma unroll
        for (int nt = 0; nt < 4; ++nt) {
            const int nrow = nt*16 + frow;
            bf16x8 b = *(const bf16x8*)&smem[8192 + (nrow << 7) + swz(nrow, kt*32 + kofs)];
            accB[nt] = __builtin_amdgcn_mfma_f32_16x16x32_bf16(a, b, accB[nt], 0, 0, 0);
        }
    }
    __syncthreads();   // all phase-B reads of smem complete

    // ---- build concat tile in smem[0..12288): [64][192] swizzled ----
    // nn -> k' 0..49
    #pragma unroll
    for (int nt = 0; nt < 4; ++nt) {
        const int g = nt*16 + frow;
        if (g < 50) {
            const float bias = sb[g];
            #pragma unroll
            for (int r = 0; r < 4; ++r) {
                const int row = rbase + r;
                smem[row*192 + swz(row, g)] = f2bf(fmaxf(accB[nt][r] + bias, 0.f));
            }
        }
    }
    // en hi/lo -> k' 50..99 / 100..149
    for (int i = tid; i < 4096; i += 256) {
        const int row = i >> 6, q = i & 63;
        if (q < 50) {
            float en = 0.f;
            const int gr = n0 + row;
            if (gr < V_N) en = node_out[(size_t)gr*HH + q];
            const u16 hi = f2bf(en);
            const u16 lo = f2bf(en - bf2f(hi));
            smem[row*192 + swz(row,  50 + q)] = hi;
            smem[row*192 + swz(row, 100 + q)] = lo;
        }
    }
    // zeros -> k' 150..191
    for (int i = tid; i < 4096; i += 256) {
        const int row = i >> 6, q = i & 63;
        if (q < 42) smem[row*192 + swz(row, 150 + q)] = 0;
    }
    __syncthreads();

    // ---- phase C: new_node = relu(concat @ swu + bU) ----
    f32x4 accC[4];
    #pragma unroll
    for (int nt = 0; nt < 4; ++nt) accC[nt] = zf;
    #pragma unroll
    for (int kt = 0; kt < 6; ++kt) {
        bf16x8 a = *(const bf16x8*)&smem[arow*192 + swz(arow, kt*32 + kofs)];
        #pragma unroll
        for (int nt = 0; nt < 4; ++nt) {
            const int nrow = nt*16 + frow;
            bf16x8 b = *(const bf16x8*)&swu[nrow*192 + swz(nrow, kt*32 + kofs)];
            accC[nt] = __builtin_amdgcn_mfma_f32_16x16x32_bf16(a, b, accC[nt], 0, 0, 0);
        }
    }
    #pragma unroll
    for (int nt = 0; nt < 4; ++nt) {
        const int g = nt*16 + frow;
        if (g < 50) {
            const float bias = sb[64 + g];
            #pragma unroll
            for (int r = 0; r < 4; ++r) {
                const int gr = n0 + rbase + r;
                if (gr < V_N)
                    node_out[(size_t)gr*HH + g] = fmaxf(accC[nt][r] + bias, 0.f);
            }
        }
    }
}

extern "C" void kernel_launch(void* const* d_in, const int* in_sizes, int n_in,
                              void* d_out, int out_size, void* d_ws, size_t ws_size,
                              hipStream_t stream) {
    const float* nf    = (const float*)d_in[0];
    const float* ef    = (const float*)d_in[1];
    const int*   src   = (const int*)d_in[2];
    const int*   dst   = (const int*)d_in[3];
    const float* w_n2n = (const float*)d_in[4];  const float* b_n2n = (const float*)d_in[5];
    const float* w_e2n = (const float*)d_in[6];  const float* b_e2n = (const float*)d_in[7];
    const float* w_updn= (const float*)d_in[8];  const float* b_updn= (const float*)d_in[9];
    const float* w_l   = (const float*)d_in[10]; const float* b_l   = (const float*)d_in[11];
    const float* w_r   = (const float*)d_in[12]; const float* b_r   = (const float*)d_in[13];
    const float* w_e2e = (const float*)d_in[14]; const float* b_e2e = (const float*)d_in[15];
    const float* w_upde= (const float*)d_in[16]; const float* b_upde= (const float*)d_in[17];

    // workspace layout: [0,10MB) left bf16 (V x 50), [10,20MB) right bf16
    char* ws = (char*)d_ws;
    u16* left  = (u16*)ws;
    u16* right = (u16*)(ws + 10000000);

    float* out_node = (float*)d_out;   // doubles as edge_node fp32 accumulator
    float* out_edge = out_node + (size_t)V_N * HH;

    hipMemsetAsync(out_node, 0, (size_t)V_N * HH * sizeof(float), stream);

    k_lr<<<(V_N + 63)/64, 256, 0, stream>>>(nf, w_l, b_l, w_r, b_r, left, right);

    k_edge<<<E_N/(64*TPB), 256, 0, stream>>>(
        ef, src, dst, w_e2n, b_e2n, w_e2e, b_e2e, w_upde, b_upde,
        left, right, out_node, out_edge);

    k_node_upd<<<(V_N + 63)/64, 256, 0, stream>>>(
        nf, w_n2n, b_n2n, w_updn, b_updn, out_node);
}